// Round 2
// baseline (94.751 us; speedup 1.0000x reference)
//
#include <hip/hip_runtime.h>
#include <math.h>

#define BDIM 8
#define SDIM 2048
#define EDIM 512
#define LDIM 128
#define MTOT (BDIM * SDIM)   // 16384

typedef __attribute__((ext_vector_type(8))) short s8v;    // 8 bf16 (4 VGPRs) MFMA frag
typedef __attribute__((ext_vector_type(4))) float f4v;

__device__ __forceinline__ unsigned short f2bf(float x) {
    union { float f; unsigned u; } c; c.f = x;
    return (unsigned short)((c.u + 0x7fffu + ((c.u >> 16) & 1u)) >> 16);  // RNE
}

// ---- prep: Bmat(bf16, [L][E] = B^T layout), m2[l], inv_var, coef ----
__global__ __launch_bounds__(64) void gs_prep(
    const float* __restrict__ means, const float* __restrict__ var,
    unsigned short* __restrict__ Bmat, float* __restrict__ m2,
    float* __restrict__ ivbuf, float* __restrict__ coef)
{
    const int l = blockIdx.x;    // 0..127
    const int t = threadIdx.x;   // 0..63
    const int e0 = t * 8;

    float mv[8], iv[8];
    const float* mrow = means + l * EDIM + e0;
#pragma unroll
    for (int i = 0; i < 8; ++i) { mv[i] = mrow[i]; iv[i] = 1.0f / var[e0 + i]; }

    float part = 0.0f;
    s8v pr;
#pragma unroll
    for (int i = 0; i < 8; ++i) {
        float p = mv[i] * iv[i];            // means * inv_var
        pr[i] = (short)f2bf(p);
        part += mv[i] * p;                  // means^2 * inv_var
    }
    *(s8v*)(Bmat + l * EDIM + e0) = pr;

#pragma unroll
    for (int off = 32; off > 0; off >>= 1) part += __shfl_down(part, off, 64);
    if (t == 0) m2[l] = part;

    if (l == 0) {
#pragma unroll
        for (int i = 0; i < 8; ++i) ivbuf[e0 + i] = iv[i];
        float ld = 0.0f;
#pragma unroll
        for (int i = 0; i < 8; ++i) ld += logf(var[e0 + i]);
#pragma unroll
        for (int off = 32; off > 0; off >>= 1) ld += __shfl_down(ld, off, 64);
        if (t == 0) {
            const float factor = -(float)EDIM * 0.5f * 1.8378770664093453f; // ln(2*pi)
            *coef = factor - 0.5f * ld;
        }
    }
}

// ---- main: barrier-free per-wave GEMM. Each wave: 16 rows x 128 cols.
// A-fragment loaded directly from global in MFMA layout (row=lane&15,
// k=quad*8..+7), converted fp32->bf16 in-register with fused e2.
// B-fragments read from L2-resident Bmat. Register ring buffers:
// A depth 4 (HBM ~900cyc), B/iv depth 2 (L2 ~200cyc).
__global__ __launch_bounds__(128) void gs_main(
    const float* __restrict__ emb, const unsigned short* __restrict__ Bmat,
    const float* __restrict__ m2, const float* __restrict__ ivbuf,
    const float* __restrict__ coef, float* __restrict__ out)
{
    const int t    = threadIdx.x;
    const int lane = t & 63;
    const int wave = t >> 6;          // 0..1
    const int q    = lane >> 4;       // quad 0..3
    const int fr   = lane & 15;       // fragment row (A) / col (B)
    const int m0   = blockIdx.x * 32 + wave * 16;

    const float*          ap  = emb   + (size_t)(m0 + fr) * EDIM + q * 8;
    const unsigned short* bp  = Bmat  + fr * EDIM + q * 8;
    const float*          ivp = ivbuf + q * 8;

    f4v acc[8];
#pragma unroll
    for (int i = 0; i < 8; ++i) acc[i] = (f4v)0.0f;

    // ring buffers
    f4v a0[4], a1[4];     // A: depth 4
    f4v v0[2], v1[2];     // inv_var: depth 2
    s8v bf[2][8];         // B: depth 2

#pragma unroll
    for (int p = 0; p < 4; ++p) {
        a0[p] = *(const f4v*)(ap + 32 * p);
        a1[p] = *(const f4v*)(ap + 32 * p + 4);
    }
#pragma unroll
    for (int p = 0; p < 2; ++p) {
        v0[p] = *(const f4v*)(ivp + 32 * p);
        v1[p] = *(const f4v*)(ivp + 32 * p + 4);
#pragma unroll
        for (int ct = 0; ct < 8; ++ct)
            bf[p][ct] = *(const s8v*)(bp + ct * 16 * EDIM + 32 * p);
    }

    float e2acc = 0.0f;

#pragma unroll
    for (int s = 0; s < 16; ++s) {
        // snapshot current step's regs (renamed away by the allocator)
        f4v xa = a0[s & 3], xb = a1[s & 3];
        f4v va = v0[s & 1], vb = v1[s & 1];
        s8v bcur[8];
#pragma unroll
        for (int ct = 0; ct < 8; ++ct) bcur[ct] = bf[s & 1][ct];

        // prefetch
        if (s + 4 < 16) {
            a0[(s + 4) & 3] = *(const f4v*)(ap + 32 * (s + 4));
            a1[(s + 4) & 3] = *(const f4v*)(ap + 32 * (s + 4) + 4);
        }
        if (s + 2 < 16) {
            v0[s & 1] = *(const f4v*)(ivp + 32 * (s + 2));
            v1[s & 1] = *(const f4v*)(ivp + 32 * (s + 2) + 4);
#pragma unroll
            for (int ct = 0; ct < 8; ++ct)
                bf[s & 1][ct] = *(const s8v*)(bp + ct * 16 * EDIM + 32 * (s + 2));
        }

        // convert + fused e2
        s8v af;
#pragma unroll
        for (int i = 0; i < 4; ++i) {
            af[i] = (short)f2bf(xa[i]);
            e2acc += xa[i] * xa[i] * va[i];
        }
#pragma unroll
        for (int i = 0; i < 4; ++i) {
            af[4 + i] = (short)f2bf(xb[i]);
            e2acc += xb[i] * xb[i] * vb[i];
        }

#pragma unroll
        for (int ct = 0; ct < 8; ++ct)
            acc[ct] = __builtin_amdgcn_mfma_f32_16x16x32_bf16(af, bcur[ct], acc[ct], 0, 0, 0);
    }

    // e2: sum the 4 quads holding row fr's k-partials
    e2acc += __shfl_xor(e2acc, 16, 64);
    e2acc += __shfl_xor(e2acc, 32, 64);
    // every lane now holds e2[lane&15]; gather e2 for C-layout rows q*4+r
    float e2row[4];
#pragma unroll
    for (int r = 0; r < 4; ++r) e2row[r] = __shfl(e2acc, q * 4 + r, 64);

    const float cf = *coef;
#pragma unroll
    for (int ct = 0; ct < 8; ++ct) {
        const int n = ct * 16 + fr;
        const float cm = cf - 0.5f * m2[n];
#pragma unroll
        for (int r = 0; r < 4; ++r) {
            const int row = q * 4 + r;     // C/D: col=lane&15, row=quad*4+reg
            out[(size_t)(m0 + row) * LDIM + n] = acc[ct][r] + cm - 0.5f * e2row[r];
        }
    }
}

extern "C" void kernel_launch(void* const* d_in, const int* in_sizes, int n_in,
                              void* d_out, int out_size, void* d_ws, size_t ws_size,
                              hipStream_t stream) {
    const float* emb   = (const float*)d_in[0];
    const float* means = (const float*)d_in[1];
    const float* var   = (const float*)d_in[2];
    float* out = (float*)d_out;

    char* ws = (char*)d_ws;
    unsigned short* Bmat = (unsigned short*)ws;          // 131072 B
    float* m2    = (float*)(ws + 131072);                // 512 B
    float* ivbuf = (float*)(ws + 131584);                // 2048 B
    float* coef  = (float*)(ws + 133632);                // 4 B

    gs_prep<<<LDIM, 64, 0, stream>>>(means, var, Bmat, m2, ivbuf, coef);
    gs_main<<<MTOT / 32, 128, 0, stream>>>(emb, Bmat, m2, ivbuf, coef, out);
}

// Round 3
// 93.806 us; speedup vs baseline: 1.0101x; 1.0101x over previous
//
#include <hip/hip_runtime.h>
#include <math.h>

#define EDIM 512
#define LDIM 128
#define MTOT 16384   // 8*2048 tokens

typedef __attribute__((ext_vector_type(8))) short s8v;    // 8 bf16 (4 VGPRs) MFMA frag
typedef __attribute__((ext_vector_type(4))) float f4v;

__device__ __forceinline__ unsigned short f2bf(float x) {
    union { float f; unsigned u; } c; c.f = x;
    return (unsigned short)((c.u + 0x7fffu + ((c.u >> 16) & 1u)) >> 16);  // RNE
}

// ---- prep: Bmat(bf16, [L][E] = B^T layout), m2[l], inv_var, coef ----
__global__ __launch_bounds__(64) void gs_prep(
    const float* __restrict__ means, const float* __restrict__ var,
    unsigned short* __restrict__ Bmat, float* __restrict__ m2,
    float* __restrict__ ivbuf, float* __restrict__ coef)
{
    const int l = blockIdx.x;    // 0..127
    const int t = threadIdx.x;   // 0..63
    const int e0 = t * 8;

    float mv[8], iv[8];
    const float* mrow = means + l * EDIM + e0;
#pragma unroll
    for (int i = 0; i < 8; ++i) { mv[i] = mrow[i]; iv[i] = 1.0f / var[e0 + i]; }

    float part = 0.0f;
    s8v pr;
#pragma unroll
    for (int i = 0; i < 8; ++i) {
        float p = mv[i] * iv[i];            // means * inv_var
        pr[i] = (short)f2bf(p);
        part += mv[i] * p;                  // means^2 * inv_var
    }
    *(s8v*)(Bmat + l * EDIM + e0) = pr;

#pragma unroll
    for (int off = 32; off > 0; off >>= 1) part += __shfl_down(part, off, 64);
    if (t == 0) m2[l] = part;

    if (l == 0) {
#pragma unroll
        for (int i = 0; i < 8; ++i) ivbuf[e0 + i] = iv[i];
        float ld = 0.0f;
#pragma unroll
        for (int i = 0; i < 8; ++i) ld += logf(var[e0 + i]);
#pragma unroll
        for (int off = 32; off > 0; off >>= 1) ld += __shfl_down(ld, off, 64);
        if (t == 0) {
            const float factor = -(float)EDIM * 0.5f * 1.8378770664093453f; // ln(2*pi)
            *coef = factor - 0.5f * ld;
        }
    }
}

// ---- main: per-wave 16x128 GEMM stripe. B staged in LDS in fragment-packed
// layout (2 K-passes of 256, 64 KB, conflict-free b128), A read directly from
// global in MFMA fragment layout with a depth-4 register ring (vmcnt only),
// B reads on the DS pipe (lgkmcnt) -> the two streams don't serialize.
// Barriers only at pass boundaries (2 per pass), not per step.
__global__ __launch_bounds__(128) void gs_main(
    const float* __restrict__ emb, const unsigned short* __restrict__ Bmat,
    const float* __restrict__ m2, const float* __restrict__ ivbuf,
    const float* __restrict__ coef, float* __restrict__ out)
{
    // 64 frags (s=0..7, ct=0..7) x 64 lanes x 8 shorts = 65536 B
    __shared__ __align__(16) unsigned short Blds[64 * 64 * 8];

    const int t    = threadIdx.x;
    const int lane = t & 63;
    const int wave = t >> 6;          // 0..1
    const int q    = lane >> 4;       // quad 0..3
    const int fr   = lane & 15;       // fragment row (A) / col (B)
    const int m0   = blockIdx.x * 32 + wave * 16;

    const float* ap  = emb   + (size_t)(m0 + fr) * EDIM + q * 8;
    const float* ivp = ivbuf + q * 8;

    // A ring: depth 4 (HBM ~900 cyc). Issue first - longest latency.
    f4v a0[4], a1[4];
#pragma unroll
    for (int p = 0; p < 4; ++p) {
        a0[p] = *(const f4v*)(ap + 32 * p);
        a1[p] = *(const f4v*)(ap + 32 * p + 4);
    }
    // iv ring: depth 2 (L2-resident)
    f4v v0[2], v1[2];
#pragma unroll
    for (int p = 0; p < 2; ++p) {
        v0[p] = *(const f4v*)(ivp + 32 * p);
        v1[p] = *(const f4v*)(ivp + 32 * p + 4);
    }

    f4v acc[8];
#pragma unroll
    for (int i = 0; i < 8; ++i) acc[i] = (f4v)0.0f;
    float e2acc = 0.0f;

#pragma unroll
    for (int pass = 0; pass < 2; ++pass) {
        if (pass) __syncthreads();               // all waves done reading pass-0 frags
        // stage 64 KB of B for k in [pass*256, pass*256+256)
        {
            const int kb = pass * 256;
#pragma unroll 16
            for (int c = 0; c < 32; ++c) {
                const int fl  = c * 128 + t;      // flat frag-lane id
                const int frg = fl >> 6;          // 0..63: s = frg>>3, ct = frg&7
                const int ln  = fl & 63;
                const int col = (frg & 7) * 16 + (ln & 15);
                const int k   = kb + (frg >> 3) * 32 + (ln >> 4) * 8;
                *(s8v*)&Blds[fl * 8] = *(const s8v*)(Bmat + col * EDIM + k);
            }
        }
        __syncthreads();

#pragma unroll
        for (int ss = 0; ss < 8; ++ss) {
            const int s = pass * 8 + ss;
            // snapshot current slots before overwriting
            f4v xa = a0[s & 3], xb = a1[s & 3];
            f4v va = v0[s & 1], vb = v1[s & 1];

            // iv prefetch ISSUED BEFORE A prefetch: vmcnt completes in issue
            // order, so iv[s+2] must not queue behind the young A[s+4] load.
            if (s + 2 < 16) {
                v0[s & 1] = *(const f4v*)(ivp + 32 * (s + 2));
                v1[s & 1] = *(const f4v*)(ivp + 32 * (s + 2) + 4);
            }
            if (s + 4 < 16) {
                a0[s & 3] = *(const f4v*)(ap + 32 * (s + 4));
                a1[s & 3] = *(const f4v*)(ap + 32 * (s + 4) + 4);
            }

            // convert + fused e2
            s8v af;
#pragma unroll
            for (int i = 0; i < 4; ++i) {
                af[i] = (short)f2bf(xa[i]);
                e2acc += xa[i] * xa[i] * va[i];
            }
#pragma unroll
            for (int i = 0; i < 4; ++i) {
                af[4 + i] = (short)f2bf(xb[i]);
                e2acc += xb[i] * xb[i] * vb[i];
            }

            // B frags from LDS: consecutive-lane b128 -> conflict-free
            const unsigned short* bbase = &Blds[(ss * 8) * 64 * 8 + lane * 8];
#pragma unroll
            for (int ct = 0; ct < 8; ++ct) {
                s8v bfv = *(const s8v*)(bbase + ct * 64 * 8);
                acc[ct] = __builtin_amdgcn_mfma_f32_16x16x32_bf16(af, bfv, acc[ct], 0, 0, 0);
            }
        }
    }

    // e2: sum the 4 quads' k-partials for each row
    e2acc += __shfl_xor(e2acc, 16, 64);
    e2acc += __shfl_xor(e2acc, 32, 64);
    float e2row[4];
#pragma unroll
    for (int r = 0; r < 4; ++r) e2row[r] = __shfl(e2acc, q * 4 + r, 64);

    const float cf = *coef;
#pragma unroll
    for (int ct = 0; ct < 8; ++ct) {
        const int n = ct * 16 + fr;
        const float cm = cf - 0.5f * m2[n];
#pragma unroll
        for (int r = 0; r < 4; ++r) {
            const int row = q * 4 + r;     // C/D: col=lane&15, row=quad*4+reg
            out[(size_t)(m0 + row) * LDIM + n] = acc[ct][r] + cm - 0.5f * e2row[r];
        }
    }
}

extern "C" void kernel_launch(void* const* d_in, const int* in_sizes, int n_in,
                              void* d_out, int out_size, void* d_ws, size_t ws_size,
                              hipStream_t stream) {
    const float* emb   = (const float*)d_in[0];
    const float* means = (const float*)d_in[1];
    const float* var   = (const float*)d_in[2];
    float* out = (float*)d_out;

    char* ws = (char*)d_ws;
    unsigned short* Bmat = (unsigned short*)ws;          // 131072 B
    float* m2    = (float*)(ws + 131072);                // 512 B
    float* ivbuf = (float*)(ws + 131584);                // 2048 B
    float* coef  = (float*)(ws + 133632);                // 4 B

    gs_prep<<<LDIM, 64, 0, stream>>>(means, var, Bmat, m2, ivbuf, coef);
    gs_main<<<MTOT / 32, 128, 0, stream>>>(emb, Bmat, m2, ivbuf, coef, out);
}

// Round 4
// 90.135 us; speedup vs baseline: 1.0512x; 1.0407x over previous
//
#include <hip/hip_runtime.h>
#include <math.h>

#define EDIM 512
#define LDIM 128
#define MTOT 16384   // 8*2048 tokens
#define TM 32        // rows per block
#define BK 64        // k-chunk
#define LSTR 72      // A LDS row stride in shorts (144 B: 16B-aligned, rotates banks)

typedef __attribute__((ext_vector_type(8))) short s8v;    // 8 bf16 (4 VGPRs) MFMA frag
typedef __attribute__((ext_vector_type(4))) float f4v;

__device__ __forceinline__ unsigned short f2bf(float x) {
    union { float f; unsigned u; } c; c.f = x;
    return (unsigned short)((c.u + 0x7fffu + ((c.u >> 16) & 1u)) >> 16);  // RNE
}

__device__ __forceinline__ void ld_lds16(const void* g, void* l) {
    __builtin_amdgcn_global_load_lds(
        (const __attribute__((address_space(1))) unsigned int*)g,
        (__attribute__((address_space(3))) unsigned int*)l, 16, 0, 0);
}

// ---- prep: Bmat(bf16, [L][E] = B^T layout), m2[l], inv_var, coef ----
__global__ __launch_bounds__(64) void gs_prep(
    const float* __restrict__ means, const float* __restrict__ var,
    unsigned short* __restrict__ Bmat, float* __restrict__ m2,
    float* __restrict__ ivbuf, float* __restrict__ coef)
{
    const int l = blockIdx.x;    // 0..127
    const int t = threadIdx.x;   // 0..63
    const int e0 = t * 8;

    float mv[8], iv[8];
    const float* mrow = means + l * EDIM + e0;
#pragma unroll
    for (int i = 0; i < 8; ++i) { mv[i] = mrow[i]; iv[i] = 1.0f / var[e0 + i]; }

    float part = 0.0f;
    s8v pr;
#pragma unroll
    for (int i = 0; i < 8; ++i) {
        float p = mv[i] * iv[i];            // means * inv_var
        pr[i] = (short)f2bf(p);
        part += mv[i] * p;                  // means^2 * inv_var
    }
    *(s8v*)(Bmat + l * EDIM + e0) = pr;

#pragma unroll
    for (int off = 32; off > 0; off >>= 1) part += __shfl_down(part, off, 64);
    if (t == 0) m2[l] = part;

    if (l == 0) {
#pragma unroll
        for (int i = 0; i < 8; ++i) ivbuf[e0 + i] = iv[i];
        float ld = 0.0f;
#pragma unroll
        for (int i = 0; i < 8; ++i) ld += logf(var[e0 + i]);
#pragma unroll
        for (int off = 32; off > 0; off >>= 1) ld += __shfl_down(ld, off, 64);
        if (t == 0) {
            const float factor = -(float)EDIM * 0.5f * 1.8378770664093453f; // ln(2*pi)
            *coef = factor - 0.5f * ld;
        }
    }
}

// ---- main: R1 skeleton + software pipeline.
//  A: coalesced global->reg (depth-2 ring) -> convert(+fused e2) -> LDS dbuf.
//  B: global_load_lds width-16 into fragment-packed LDS dbuf, 1 chunk ahead,
//     issued right AFTER the barrier so the pre-barrier vmcnt(0) drain only
//     sees iteration-old loads. One barrier per chunk.
__global__ __launch_bounds__(256) void gs_main(
    const float* __restrict__ emb, const unsigned short* __restrict__ Bmat,
    const float* __restrict__ m2, const float* __restrict__ ivbuf,
    const float* __restrict__ coef, float* __restrict__ out)
{
    __shared__ __align__(16) unsigned short Alds[2][TM][LSTR];     // 2*4608 B
    __shared__ __align__(16) unsigned short Blds[2][16 * 64 * 8];  // 2*16 KB
    __shared__ float e2part[256];
    __shared__ float e2s[TM];

    const int t    = threadIdx.x;
    const int lane = t & 63;
    const int w    = t >> 6;          // wave 0..3
    const int q    = lane >> 4;       // quad
    const int fr   = lane & 15;
    const int m0   = blockIdx.x * TM;

    // staging map (A): thread covers (arow, kseg..kseg+7)
    const int arow = t >> 3;          // 0..31
    const int kseg = (t & 7) * 8;     // 0..56

    // compute map: wave grid 2x2 over 32 rows x 128 cols
    const int r0w = (w >> 1) * 16;
    const int c0w1 = (w & 1) * 4;     // col-tile offset (in 16-col tiles)

    const float* ap  = emb   + (size_t)(m0 + arow) * EDIM + kseg;
    const float* ivp = ivbuf + kseg;

    f4v acc[4];
#pragma unroll
    for (int i = 0; i < 4; ++i) acc[i] = (f4v)0.0f;
    float e2acc = 0.0f;

    // A / iv register rings, depth 2
    f4v ar0[2], ar1[2], vr0[2], vr1[2];
    ar0[0] = *(const f4v*)(ap);          ar1[0] = *(const f4v*)(ap + 4);
    ar0[1] = *(const f4v*)(ap + BK);     ar1[1] = *(const f4v*)(ap + BK + 4);
    vr0[0] = *(const f4v*)(ivp);         vr1[0] = *(const f4v*)(ivp + 4);
    vr0[1] = *(const f4v*)(ivp + BK);    vr1[1] = *(const f4v*)(ivp + BK + 4);

    // B staging: 16 frags/chunk (F = ks_i*8 + ctile), wave w issues F=w*4..w*4+3.
    // LDS dest = Blds[buf] + F*1024B (wave-uniform); HW scatters lane*16B.
#define STAGE_B(kc, buf)                                                        \
    {                                                                           \
        _Pragma("unroll")                                                       \
        for (int j = 0; j < 4; ++j) {                                           \
            const int F   = w * 4 + j;                                          \
            const int col = (F & 7) * 16 + fr;                                  \
            const int kk  = (kc) * BK + (F >> 3) * 32 + q * 8;                  \
            ld_lds16(Bmat + col * EDIM + kk, (void*)&Blds[buf][F * 512]);       \
        }                                                                       \
    }

    STAGE_B(0, 0)

#pragma unroll
    for (int kc = 0; kc < EDIM / BK; ++kc) {
        const int b = kc & 1;

        // convert current A regs + fused e2 (waits only on its own 2-iter-old loads)
        f4v xa = ar0[b], xb = ar1[b], va = vr0[b], vb = vr1[b];
        s8v a8;
#pragma unroll
        for (int i = 0; i < 4; ++i) {
            a8[i] = (short)f2bf(xa[i]);
            e2acc += xa[i] * xa[i] * va[i];
        }
#pragma unroll
        for (int i = 0; i < 4; ++i) {
            a8[4 + i] = (short)f2bf(xb[i]);
            e2acc += xb[i] * xb[i] * vb[i];
        }
        *(s8v*)&Alds[b][arow][kseg] = a8;

        __syncthreads();   // drains B(kc) lds-loads + iteration-old A/iv prefetches

        // prefetches for the NEXT iterations (issued after the drain point)
        if (kc + 1 < EDIM / BK) STAGE_B(kc + 1, b ^ 1)
        if (kc + 2 < EDIM / BK) {
            const int k2 = (kc + 2) * BK;
            ar0[b] = *(const f4v*)(ap + k2);  ar1[b] = *(const f4v*)(ap + k2 + 4);
            vr0[b] = *(const f4v*)(ivp + k2); vr1[b] = *(const f4v*)(ivp + k2 + 4);
        }

        // MFMA on buffers b
#pragma unroll
        for (int ks_i = 0; ks_i < 2; ++ks_i) {
            s8v af = *(const s8v*)&Alds[b][r0w + fr][ks_i * 32 + q * 8];
#pragma unroll
            for (int ct = 0; ct < 4; ++ct) {
                const int F = ks_i * 8 + c0w1 + ct;
                s8v bfv = *(const s8v*)&Blds[b][F * 512 + lane * 8];
                acc[ct] = __builtin_amdgcn_mfma_f32_16x16x32_bf16(af, bfv, acc[ct], 0, 0, 0);
            }
        }
        // next iter writes Alds[b^1]/reads Blds[b^1]: readers of those finished
        // before THIS iteration's barrier -> one barrier per chunk is enough.
    }

    // e2 reduction: row r's k-partials live in threads 8r..8r+7
    e2part[t] = e2acc;
    __syncthreads();
    if (t < TM) {
        float s = 0.0f;
#pragma unroll
        for (int j = 0; j < 8; ++j) s += e2part[t * 8 + j];
        e2s[t] = s;
    }
    __syncthreads();

    const float cf = *coef;
#pragma unroll
    for (int ct = 0; ct < 4; ++ct) {
        const int n = (c0w1 + ct) * 16 + fr;
        const float cm = cf - 0.5f * m2[n];
#pragma unroll
        for (int r = 0; r < 4; ++r) {
            const int row = r0w + q * 4 + r;   // C/D: col=lane&15, row=quad*4+reg
            out[(size_t)(m0 + row) * LDIM + n] = acc[ct][r] + cm - 0.5f * e2s[row];
        }
    }
#undef STAGE_B
}

extern "C" void kernel_launch(void* const* d_in, const int* in_sizes, int n_in,
                              void* d_out, int out_size, void* d_ws, size_t ws_size,
                              hipStream_t stream) {
    const float* emb   = (const float*)d_in[0];
    const float* means = (const float*)d_in[1];
    const float* var   = (const float*)d_in[2];
    float* out = (float*)d_out;

    char* ws = (char*)d_ws;
    unsigned short* Bmat = (unsigned short*)ws;          // 131072 B
    float* m2    = (float*)(ws + 131072);                // 512 B
    float* ivbuf = (float*)(ws + 131584);                // 2048 B
    float* coef  = (float*)(ws + 133632);                // 4 B

    gs_prep<<<LDIM, 64, 0, stream>>>(means, var, Bmat, m2, ivbuf, coef);
    gs_main<<<MTOT / TM, 256, 0, stream>>>(emb, Bmat, m2, ivbuf, coef, out);
}

// Round 5
// 86.034 us; speedup vs baseline: 1.1013x; 1.0477x over previous
//
#include <hip/hip_runtime.h>
#include <math.h>

#define EDIM 512
#define LDIM 128
#define MTOT 16384   // 8*2048 tokens
#define TM 16        // rows per block
#define BK 64        // k-chunk
#define NCHUNK (EDIM / BK)   // 8
#define LSTR 72      // A LDS row stride in shorts (144 B, 16B-aligned)

typedef __attribute__((ext_vector_type(8))) short s8v;    // 8 bf16 MFMA frag
typedef __attribute__((ext_vector_type(4))) short s4v;
typedef __attribute__((ext_vector_type(4))) float f4v;

__device__ __forceinline__ unsigned short f2bf(float x) {
    union { float f; unsigned u; } c; c.f = x;
    return (unsigned short)((c.u + 0x7fffu + ((c.u >> 16) & 1u)) >> 16);  // RNE
}

__device__ __forceinline__ void ld_lds16(const void* g, void* l) {
    __builtin_amdgcn_global_load_lds(
        (const __attribute__((address_space(1))) unsigned int*)g,
        (__attribute__((address_space(3))) unsigned int*)l, 16, 0, 0);
}

// ---- prep: Bfrag = bf16(means*inv_var) pre-packed in MFMA-fragment-linear
// order: byte addr = kc*16384 + F*1024 + lane*16, where F=(ks_i*8 + ct),
// frag element (col = (F&7)*16 + (lane&15), k = kc*64 + (F>>3)*32 + (lane>>4)*8 + j).
// Also m2[l], inv_var, coef.
__global__ __launch_bounds__(64) void gs_prep(
    const float* __restrict__ means, const float* __restrict__ var,
    unsigned short* __restrict__ Bfrag, float* __restrict__ m2,
    float* __restrict__ ivbuf, float* __restrict__ coef)
{
    const int l = blockIdx.x;    // 0..127 (= col = ct*16 + fr)
    const int t = threadIdx.x;   // 0..63  (= kc*8 + ks_i*4 + q)
    const int e0 = t * 8;

    float mv[8], iv[8];
    const float* mrow = means + l * EDIM + e0;
#pragma unroll
    for (int i = 0; i < 8; ++i) { mv[i] = mrow[i]; iv[i] = 1.0f / var[e0 + i]; }

    float part = 0.0f;
    s8v pr;
#pragma unroll
    for (int i = 0; i < 8; ++i) {
        float p = mv[i] * iv[i];            // means * inv_var
        pr[i] = (short)f2bf(p);
        part += mv[i] * p;                  // means^2 * inv_var
    }
    // fragment-packed address (in shorts)
    {
        const int kc   = t >> 3;
        const int ks_i = (t >> 2) & 1;
        const int q    = t & 3;
        const int F    = ks_i * 8 + (l >> 4);
        const int ln   = q * 16 + (l & 15);
        *(s8v*)(Bfrag + kc * 8192 + F * 512 + ln * 8) = pr;
    }

#pragma unroll
    for (int off = 32; off > 0; off >>= 1) part += __shfl_down(part, off, 64);
    if (t == 0) m2[l] = part;

    if (l == 0) {
#pragma unroll
        for (int i = 0; i < 8; ++i) ivbuf[e0 + i] = iv[i];
        float ld = 0.0f;
#pragma unroll
        for (int i = 0; i < 8; ++i) ld += logf(var[e0 + i]);
#pragma unroll
        for (int off = 32; off > 0; off >>= 1) ld += __shfl_down(ld, off, 64);
        if (t == 0) {
            const float factor = -(float)EDIM * 0.5f * 1.8378770664093453f; // ln(2*pi)
            *coef = factor - 0.5f * ld;
        }
    }
}

// ---- main: 16x128 tile per block, 1024 blocks (4/CU, 16 waves/CU).
//  A: coalesced global->reg ring (depth 2) -> convert(+fused e2) -> LDS dbuf.
//  B: 4x ld_lds16 per wave per chunk from fragment-LINEAR Bfrag (uniform LDS
//     base + lane*16 = exactly the HW pattern; consecutive-line coalesced).
//  One barrier per chunk.
__global__ __launch_bounds__(256, 4) void gs_main(
    const float* __restrict__ emb, const unsigned short* __restrict__ Bfrag,
    const float* __restrict__ m2, const float* __restrict__ ivbuf,
    const float* __restrict__ coef, float* __restrict__ out)
{
    __shared__ __align__(16) unsigned short Alds[2][TM][LSTR];     // 2*2304 B
    __shared__ __align__(16) unsigned short Blds[2][16 * 64 * 8];  // 2*16 KB
    __shared__ float e2part[256];
    __shared__ float e2s[TM];

    const int t    = threadIdx.x;
    const int lane = t & 63;
    const int w    = t >> 6;          // wave 0..3
    const int q    = lane >> 4;       // quad
    const int fr   = lane & 15;
    const int m0   = blockIdx.x * TM;

    // staging map (A): thread covers (arow, kseg..kseg+3) floats
    const int arow = t >> 4;          // 0..15
    const int kseg = (t & 15) * 4;    // 0..60

    const float* ap  = emb   + (size_t)(m0 + arow) * EDIM + kseg;
    const float* ivp = ivbuf + kseg;

    f4v acc[2];
    acc[0] = (f4v)0.0f; acc[1] = (f4v)0.0f;
    float e2acc = 0.0f;

    // A / iv register rings, depth 2
    f4v ar[2], vr[2];
    ar[0] = *(const f4v*)(ap);        ar[1] = *(const f4v*)(ap + BK);
    vr[0] = *(const f4v*)(ivp);       vr[1] = *(const f4v*)(ivp + BK);

    // B staging: copy 16 KB chunk, wave w moves 4 KB as 4 linear 1KB DMAs.
#define STAGE_B(kc, buf)                                                       \
    {                                                                          \
        const char* sb = (const char*)Bfrag + (kc) * 16384 + w * 4096;         \
        char*       db = (char*)&Blds[buf][0] + w * 4096;                      \
        _Pragma("unroll")                                                      \
        for (int j = 0; j < 4; ++j)                                            \
            ld_lds16(sb + j * 1024 + lane * 16, db + j * 1024);                \
    }

    STAGE_B(0, 0)

#pragma unroll
    for (int kc = 0; kc < NCHUNK; ++kc) {
        const int b = kc & 1;

        // convert current A regs + fused e2 (loads are 2 chunks old)
        f4v xa = ar[b], va = vr[b];
        s4v a4;
#pragma unroll
        for (int i = 0; i < 4; ++i) {
            a4[i] = (short)f2bf(xa[i]);
            e2acc += xa[i] * xa[i] * va[i];
        }
        *(s4v*)&Alds[b][arow][kseg] = a4;

        __syncthreads();   // drains B(kc) DMA + chunk-old A/iv prefetches

        // prefetches for later chunks (issued after the drain point)
        if (kc + 1 < NCHUNK) STAGE_B(kc + 1, b ^ 1)
        if (kc + 2 < NCHUNK) {
            ar[b] = *(const f4v*)(ap + (kc + 2) * BK);
            vr[b] = *(const f4v*)(ivp + (kc + 2) * BK);
        }

        // MFMA on buffers b: wave w covers cols w*32..w*32+31 (ct tiles w*2, w*2+1)
#pragma unroll
        for (int ks_i = 0; ks_i < 2; ++ks_i) {
            s8v af = *(const s8v*)&Alds[b][fr][ks_i * 32 + q * 8];
#pragma unroll
            for (int ct = 0; ct < 2; ++ct) {
                const int F = ks_i * 8 + w * 2 + ct;
                s8v bfv = *(const s8v*)&Blds[b][F * 512 + lane * 8];
                acc[ct] = __builtin_amdgcn_mfma_f32_16x16x32_bf16(af, bfv, acc[ct], 0, 0, 0);
            }
        }
    }

    // e2 reduction: row r's k-partials live in threads r*16..r*16+15
    e2part[t] = e2acc;
    __syncthreads();
    if (t < TM) {
        float s = 0.0f;
#pragma unroll
        for (int j = 0; j < 16; ++j) s += e2part[t * 16 + j];
        e2s[t] = s;
    }
    __syncthreads();

    const float cf = *coef;
#pragma unroll
    for (int ct = 0; ct < 2; ++ct) {
        const int n = (w * 2 + ct) * 16 + fr;
        const float cm = cf - 0.5f * m2[n];
#pragma unroll
        for (int r = 0; r < 4; ++r) {
            const int row = q * 4 + r;     // C/D: col=lane&15, row=quad*4+reg
            out[(size_t)(m0 + row) * LDIM + n] = acc[ct][r] + cm - 0.5f * e2s[row];
        }
    }
#undef STAGE_B
}

extern "C" void kernel_launch(void* const* d_in, const int* in_sizes, int n_in,
                              void* d_out, int out_size, void* d_ws, size_t ws_size,
                              hipStream_t stream) {
    const float* emb   = (const float*)d_in[0];
    const float* means = (const float*)d_in[1];
    const float* var   = (const float*)d_in[2];
    float* out = (float*)d_out;

    char* ws = (char*)d_ws;
    unsigned short* Bfrag = (unsigned short*)ws;         // 131072 B
    float* m2    = (float*)(ws + 131072);                // 512 B
    float* ivbuf = (float*)(ws + 131584);                // 2048 B
    float* coef  = (float*)(ws + 133632);                // 4 B

    gs_prep<<<LDIM, 64, 0, stream>>>(means, var, Bfrag, m2, ivbuf, coef);
    gs_main<<<MTOT / TM, 256, 0, stream>>>(emb, Bfrag, m2, ivbuf, coef, out);
}